// Round 1
// baseline (502.801 us; speedup 1.0000x reference)
//
#include <hip/hip_runtime.h>

// MultiHeadAttention: x[4,2048,1024] fp32, 16 heads x 64 dim, no 1/sqrt(d) scale.
// Pipeline: cvt(fp32->bf16) -> 3x gemm_bt (Q,K,V) -> flash attention -> gemm_bt (proj, fp32 out)
// All matmuls: v_mfma_f32_16x16x32_bf16, C/D layout col=lane&15, row=quad*4+reg (guide-verified).

typedef short short8 __attribute__((ext_vector_type(8)));
typedef float float4v __attribute__((ext_vector_type(4)));

#define MFMA16(a, b, c) __builtin_amdgcn_mfma_f32_16x16x32_bf16((a), (b), (c), 0, 0, 0)

#define B_SZ 4
#define T_SZ 2048
#define D_SZ 1024
#define NH 16
#define HD 64
#define M_SZ (B_SZ * T_SZ)  // 8192

__device__ __forceinline__ unsigned short f2bf(float f) {
  unsigned int u = __float_as_uint(f);
  u += 0x7fffu + ((u >> 16) & 1u);  // round-to-nearest-even
  return (unsigned short)(u >> 16);
}

// ---------------- fp32 -> bf16 convert ----------------
__global__ __launch_bounds__(256) void cvt_kernel(const float* __restrict__ in,
                                                  unsigned short* __restrict__ out,
                                                  long n) {
  long i = ((long)blockIdx.x * 256 + threadIdx.x) * 4;
  if (i >= n) return;
  float4 v = *(const float4*)(in + i);
  uint2 o;
  o.x = (unsigned)f2bf(v.x) | ((unsigned)f2bf(v.y) << 16);
  o.y = (unsigned)f2bf(v.z) | ((unsigned)f2bf(v.w) << 16);
  *(uint2*)(out + i) = o;
}

// ---------------- C[M,N] = A[M,K] * Bm[N,K]^T + bias ----------------
// 128x128 tile, BK=64. 4 waves, each owns a 64x64 quadrant (4x4 mfma tiles).
// LDS stride 72 elems (144 B) to break power-of-2 bank aliasing on b128 reads.
__global__ __launch_bounds__(256, 2) void gemm_bt(const unsigned short* __restrict__ A,
                                                  const unsigned short* __restrict__ Bm,
                                                  const float* __restrict__ bias,
                                                  unsigned short* __restrict__ Cb,
                                                  float* __restrict__ Cf,
                                                  int M, int N, int K) {
  __shared__ __align__(16) unsigned short As[128 * 72];
  __shared__ __align__(16) unsigned short Bs[128 * 72];
  const int tid = threadIdx.x;
  const int wave = tid >> 6, lane = tid & 63;
  const int q = lane >> 4, ln = lane & 15;
  const int wm = (wave >> 1) * 64, wn = (wave & 1) * 64;
  const long m0 = (long)blockIdx.y * 128;
  const long n0 = (long)blockIdx.x * 128;

  float4v acc[4][4] = {};

  for (int k0 = 0; k0 < K; k0 += 64) {
    // stage 128x64 bf16 tiles of A and B (8 chunks of 8 bf16 per row)
    for (int it = 0; it < 4; ++it) {
      int idx = tid + it * 256;  // 0..1023
      int row = idx >> 3, cc = idx & 7;
      *(uint4*)(As + row * 72 + cc * 8) =
          *(const uint4*)(A + (m0 + row) * (long)K + k0 + cc * 8);
      *(uint4*)(Bs + row * 72 + cc * 8) =
          *(const uint4*)(Bm + (n0 + row) * (long)K + k0 + cc * 8);
    }
    __syncthreads();
    for (int ks = 0; ks < 2; ++ks) {
      short8 af[4], bf[4];
      for (int i = 0; i < 4; ++i)
        af[i] = *(const short8*)(As + (wm + i * 16 + ln) * 72 + ks * 32 + q * 8);
      for (int j = 0; j < 4; ++j)
        bf[j] = *(const short8*)(Bs + (wn + j * 16 + ln) * 72 + ks * 32 + q * 8);
      for (int i = 0; i < 4; ++i)
        for (int j = 0; j < 4; ++j)
          acc[i][j] = MFMA16(af[i], bf[j], acc[i][j]);
    }
    __syncthreads();
  }

  // epilogue: C/D layout col = ln, row = q*4 + r
  for (int i = 0; i < 4; ++i) {
    long rowb = m0 + wm + i * 16 + q * 4;
    for (int j = 0; j < 4; ++j) {
      long col = n0 + wn + j * 16 + ln;
      float bv = bias[col];
      for (int r = 0; r < 4; ++r) {
        float v = acc[i][j][r] + bv;
        long off = (rowb + r) * (long)N + col;
        if (Cf) Cf[off] = v;
        else Cb[off] = f2bf(v);
      }
    }
  }
}

// ---------------- flash attention ----------------
// block = (q-tile of 128, head, batch); 256 threads = 4 waves, wave owns 32 q rows.
// kv tiles of 64. Q LDS tile is reused as the P staging buffer (wave-private rows).
__global__ __launch_bounds__(256, 2) void attn_kernel(const unsigned short* __restrict__ Qb,
                                                      const unsigned short* __restrict__ Kb,
                                                      const unsigned short* __restrict__ Vb,
                                                      unsigned short* __restrict__ Ob) {
  __shared__ __align__(16) unsigned short Qs[128 * 72];  // reused as P staging
  __shared__ __align__(16) unsigned short Ks[64 * 72];
  __shared__ __align__(16) unsigned short Vts[64 * 72];  // transposed: [dim][key]

  const int tid = threadIdx.x;
  const int wave = tid >> 6, lane = tid & 63;
  const int q = lane >> 4, ln = lane & 15;
  const int qt = blockIdx.x;  // 0..15
  const int h = blockIdx.y;   // 0..15
  const int b = blockIdx.z;   // 0..3

  const long baseQ = ((long)b * T_SZ + qt * 128) * D_SZ + h * HD;
  const long baseKV = (long)b * T_SZ * D_SZ + h * HD;

  // stage Q tile [128 x 64]
  for (int it = 0; it < 4; ++it) {
    int idx = tid + it * 256;
    int row = idx >> 3, cc = idx & 7;
    *(uint4*)(Qs + row * 72 + cc * 8) =
        *(const uint4*)(Qb + baseQ + (long)row * D_SZ + cc * 8);
  }
  __syncthreads();

  // Q frags held in registers for the whole k-loop; A layout: m=ln, k=q*8+j (+ks*32)
  short8 qf[2][2];
  for (int i = 0; i < 2; ++i)
    for (int ks = 0; ks < 2; ++ks)
      qf[i][ks] = *(const short8*)(Qs + (wave * 32 + i * 16 + ln) * 72 + ks * 32 + q * 8);

  float4v o[2][4] = {};
  float m_run[2][4], l_run[2][4];
  for (int i = 0; i < 2; ++i)
    for (int r = 0; r < 4; ++r) {
      m_run[i][r] = -1e30f;
      l_run[i][r] = 0.f;
    }

  unsigned short* Ps = Qs + wave * 32 * 72;  // this wave's private 32-row region

  for (int kt = 0; kt < 32; ++kt) {
    __syncthreads();  // protect Ks/Vts (previous iteration's readers have drained)
    // stage K [64 x 64] and V transposed [64 dims x 64 keys]
    for (int it = 0; it < 2; ++it) {
      int idx = tid + it * 256;  // 0..511
      int row = idx >> 3, cc = idx & 7;
      long g = baseKV + (long)(kt * 64 + row) * D_SZ + cc * 8;
      *(uint4*)(Ks + row * 72 + cc * 8) = *(const uint4*)(Kb + g);
      uint4 vv = *(const uint4*)(Vb + g);
      const unsigned short* vs = (const unsigned short*)&vv;
      for (int jj = 0; jj < 8; ++jj)
        Vts[(cc * 8 + jj) * 72 + row] = vs[jj];
    }
    __syncthreads();

    // S = Q K^T : per wave [32 x 64] = 2 row-tiles x 4 col-tiles
    short8 kf[4][2];
    for (int c = 0; c < 4; ++c)
      for (int ks = 0; ks < 2; ++ks)
        kf[c][ks] = *(const short8*)(Ks + (c * 16 + ln) * 72 + ks * 32 + q * 8);
    float4v s[2][4];
    for (int i = 0; i < 2; ++i)
      for (int c = 0; c < 4; ++c) {
        float4v z = {};
        z = MFMA16(qf[i][0], kf[c][0], z);
        z = MFMA16(qf[i][1], kf[c][1], z);
        s[i][c] = z;
      }

    // online softmax; rows live on 16-lane groups (fixed quad), cols = ln
    for (int i = 0; i < 2; ++i) {
      float mx[4];
      for (int r = 0; r < 4; ++r) {
        float v = fmaxf(fmaxf(s[i][0][r], s[i][1][r]), fmaxf(s[i][2][r], s[i][3][r]));
        v = fmaxf(v, __shfl_xor(v, 1, 64));
        v = fmaxf(v, __shfl_xor(v, 2, 64));
        v = fmaxf(v, __shfl_xor(v, 4, 64));
        v = fmaxf(v, __shfl_xor(v, 8, 64));
        mx[r] = v;
      }
      for (int r = 0; r < 4; ++r) {
        float m_old = m_run[i][r];
        float m_new = fmaxf(m_old, mx[r]);
        float alpha = __expf(m_old - m_new);
        float p0 = __expf(s[i][0][r] - m_new);
        float p1 = __expf(s[i][1][r] - m_new);
        float p2 = __expf(s[i][2][r] - m_new);
        float p3 = __expf(s[i][3][r] - m_new);
        float rs = p0 + p1 + p2 + p3;
        rs += __shfl_xor(rs, 1, 64);
        rs += __shfl_xor(rs, 2, 64);
        rs += __shfl_xor(rs, 4, 64);
        rs += __shfl_xor(rs, 8, 64);
        m_run[i][r] = m_new;
        l_run[i][r] = alpha * l_run[i][r] + rs;
        int prow = (i * 16 + q * 4 + r) * 72;
        Ps[prow + 0 * 16 + ln] = f2bf(p0);
        Ps[prow + 16 + ln] = f2bf(p1);
        Ps[prow + 32 + ln] = f2bf(p2);
        Ps[prow + 48 + ln] = f2bf(p3);
        for (int j = 0; j < 4; ++j) o[i][j][r] *= alpha;
      }
    }

    // O += P V : A frags from Ps (wave-private), B frags from Vts rows (= dims)
    short8 vf[4][2], pf[2][2];
    for (int j = 0; j < 4; ++j)
      for (int ks = 0; ks < 2; ++ks)
        vf[j][ks] = *(const short8*)(Vts + (j * 16 + ln) * 72 + ks * 32 + q * 8);
    for (int i = 0; i < 2; ++i)
      for (int ks = 0; ks < 2; ++ks)
        pf[i][ks] = *(const short8*)(Ps + (i * 16 + ln) * 72 + ks * 32 + q * 8);
    for (int i = 0; i < 2; ++i)
      for (int j = 0; j < 4; ++j) {
        o[i][j] = MFMA16(pf[i][0], vf[j][0], o[i][j]);
        o[i][j] = MFMA16(pf[i][1], vf[j][1], o[i][j]);
      }
  }

  // epilogue: O / l, store bf16 into [b, t, h*64+d]
  for (int i = 0; i < 2; ++i)
    for (int r = 0; r < 4; ++r) {
      float inv = 1.f / l_run[i][r];
      int row = qt * 128 + wave * 32 + i * 16 + q * 4 + r;
      long base = ((long)b * T_SZ + row) * D_SZ + h * HD;
      for (int j = 0; j < 4; ++j)
        Ob[base + j * 16 + ln] = f2bf(o[i][j][r] * inv);
    }
}

extern "C" void kernel_launch(void* const* d_in, const int* in_sizes, int n_in,
                              void* d_out, int out_size, void* d_ws, size_t ws_size,
                              hipStream_t stream) {
  const float* x = (const float*)d_in[0];
  const float* Wq = (const float*)d_in[1];
  const float* bq = (const float*)d_in[2];
  const float* Wk = (const float*)d_in[3];
  const float* bk = (const float*)d_in[4];
  const float* Wv = (const float*)d_in[5];
  const float* bv = (const float*)d_in[6];
  const float* Wp = (const float*)d_in[7];
  const float* bp = (const float*)d_in[8];
  float* out = (float*)d_out;

  const long MX = (long)M_SZ * D_SZ;  // 8388608
  const long MW = (long)D_SZ * D_SZ;  // 1048576
  unsigned short* ws = (unsigned short*)d_ws;
  unsigned short* xb = ws;
  unsigned short* Wqb = xb + MX;
  unsigned short* Wkb = Wqb + MW;
  unsigned short* Wvb = Wkb + MW;
  unsigned short* Wpb = Wvb + MW;
  unsigned short* Qb = Wpb + MW;
  unsigned short* Kb = Qb + MX;
  unsigned short* Vb = Kb + MX;
  unsigned short* Ob = Vb + MX;
  // total ws use: 46,137,344 bf16 elems = ~92.3 MB

  cvt_kernel<<<(int)(MX / 1024), 256, 0, stream>>>(x, xb, MX);
  cvt_kernel<<<(int)(MW / 1024), 256, 0, stream>>>(Wq, Wqb, MW);
  cvt_kernel<<<(int)(MW / 1024), 256, 0, stream>>>(Wk, Wkb, MW);
  cvt_kernel<<<(int)(MW / 1024), 256, 0, stream>>>(Wv, Wvb, MW);
  cvt_kernel<<<(int)(MW / 1024), 256, 0, stream>>>(Wp, Wpb, MW);

  dim3 gg(D_SZ / 128, M_SZ / 128);  // (8, 64)
  gemm_bt<<<gg, 256, 0, stream>>>(xb, Wqb, bq, Qb, nullptr, M_SZ, D_SZ, D_SZ);
  gemm_bt<<<gg, 256, 0, stream>>>(xb, Wkb, bk, Kb, nullptr, M_SZ, D_SZ, D_SZ);
  gemm_bt<<<gg, 256, 0, stream>>>(xb, Wvb, bv, Vb, nullptr, M_SZ, D_SZ, D_SZ);

  dim3 ag(T_SZ / 128, NH, B_SZ);  // (16, 16, 4)
  attn_kernel<<<ag, 256, 0, stream>>>(Qb, Kb, Vb, Ob);

  gemm_bt<<<gg, 256, 0, stream>>>(Ob, Wpb, bp, nullptr, out, M_SZ, D_SZ, D_SZ);
}

// Round 2
// 364.577 us; speedup vs baseline: 1.3791x; 1.3791x over previous
//
#include <hip/hip_runtime.h>
#include <hip/hip_bf16.h>

// MHA: x[4,2048,1024] fp32, 16 heads x 64, no 1/sqrt(d) scale.
// cvt(fp32->bf16, Wq scaled by log2e) -> gemm_bt Q,K (tok-major), V^T (feat-major)
// -> flash attention (max-free softmax, exp2) -> gemm_bt proj (fp32 out).

typedef short short8 __attribute__((ext_vector_type(8)));
typedef float float4v __attribute__((ext_vector_type(4)));

#define MFMA16(a, b, c) __builtin_amdgcn_mfma_f32_16x16x32_bf16((a), (b), (c), 0, 0, 0)
#define LOG2E 1.4426950408889634f

#define B_SZ 4
#define T_SZ 2048
#define D_SZ 1024
#define NH 16
#define HD 64
#define M_SZ (B_SZ * T_SZ)  // 8192

__device__ __forceinline__ unsigned short f2bf(float f) {
  unsigned int u = __float_as_uint(f);
  u += 0x7fffu + ((u >> 16) & 1u);
  return (unsigned short)(u >> 16);
}

__device__ __forceinline__ void gl_lds16(const unsigned short* g, unsigned short* l) {
  __builtin_amdgcn_global_load_lds(
      (const __attribute__((address_space(1))) unsigned int*)g,
      (__attribute__((address_space(3))) unsigned int*)l, 16, 0, 0);
}

// ---------------- fp32 -> bf16 convert (optional scale) ----------------
__global__ __launch_bounds__(256) void cvt_kernel(const float* __restrict__ in,
                                                  unsigned short* __restrict__ out,
                                                  float scale, long n) {
  long i = ((long)blockIdx.x * 256 + threadIdx.x) * 4;
  if (i >= n) return;
  float4 v = *(const float4*)(in + i);
  uint2 o;
  o.x = (unsigned)f2bf(v.x * scale) | ((unsigned)f2bf(v.y * scale) << 16);
  o.y = (unsigned)f2bf(v.z * scale) | ((unsigned)f2bf(v.w * scale) << 16);
  *(uint2*)(out + i) = o;
}

// ---------------- C[M,N] = A[M,K] * Bm[N,K]^T + bias ----------------
// m97 structure: 128x128 tile, BK=64, unpadded LDS, global_load_lds width=16.
__global__ __launch_bounds__(256, 2) void gemm_bt(const unsigned short* __restrict__ A,
                                                  const unsigned short* __restrict__ Bm,
                                                  const float* __restrict__ bias, float bscale,
                                                  unsigned short* __restrict__ Cb,
                                                  float* __restrict__ Cf,
                                                  int M, int N, int K, int rowbias) {
  __shared__ __align__(16) unsigned short As[128 * 64];
  __shared__ __align__(16) unsigned short Bs[128 * 64];
  const int tid = threadIdx.x;
  const int wave = tid >> 6, lane = tid & 63;
  const int q = lane >> 4, ln = lane & 15;
  const int wm = (wave >> 1) * 64, wn = (wave & 1) * 64;
  const long m0 = (long)blockIdx.y * 128;
  const long n0 = (long)blockIdx.x * 128;
  const int srow = lane >> 3, scol = (lane & 7) * 8;

  float4v acc[4][4] = {};

  for (int k0 = 0; k0 < K; k0 += 64) {
    // async stage: wave w fills LDS segments w*4+t (1024 B each, lane-linear)
    for (int t = 0; t < 4; ++t) {
      int seg = wave * 4 + t;
      int row = seg * 8 + srow;
      gl_lds16(A + (m0 + row) * (long)K + k0 + scol, As + seg * 512);
      gl_lds16(Bm + (n0 + row) * (long)K + k0 + scol, Bs + seg * 512);
    }
    __syncthreads();
    for (int ks = 0; ks < 2; ++ks) {
      short8 af[4], bf[4];
      for (int i = 0; i < 4; ++i)
        af[i] = *(const short8*)(As + (wm + i * 16 + ln) * 64 + ks * 32 + q * 8);
      for (int j = 0; j < 4; ++j)
        bf[j] = *(const short8*)(Bs + (wn + j * 16 + ln) * 64 + ks * 32 + q * 8);
      for (int i = 0; i < 4; ++i)
        for (int j = 0; j < 4; ++j)
          acc[i][j] = MFMA16(af[i], bf[j], acc[i][j]);
    }
    __syncthreads();
  }

  for (int i = 0; i < 4; ++i) {
    long rowb = m0 + wm + i * 16 + q * 4;
    for (int j = 0; j < 4; ++j) {
      long col = n0 + wn + j * 16 + ln;
      float cb = rowbias ? 0.f : bias[col] * bscale;
      for (int r = 0; r < 4; ++r) {
        float bv = rowbias ? bias[rowb + r] * bscale : cb;
        float v = acc[i][j][r] + bv;
        long off = (rowb + r) * (long)N + col;
        if (Cf) Cf[off] = v;
        else Cb[off] = f2bf(v);
      }
    }
  }
}

// ---------------- flash attention (max-free, exp2-folded) ----------------
// block = (q-tile 128, head, batch); 4 waves x 32 q-rows; kv tiles of 64.
// Q frags direct from global; Vt is pre-transposed [feat][tok].
// Pt[key][qrow] per-wave, phase-split over 32 keys. LDS total 27,648 B.
__global__ __launch_bounds__(256, 4) void attn_kernel(const unsigned short* __restrict__ Qb,
                                                      const unsigned short* __restrict__ Kb,
                                                      const unsigned short* __restrict__ Vt,
                                                      unsigned short* __restrict__ Ob) {
  __shared__ __align__(16) unsigned short Ks[64 * 72];
  __shared__ __align__(16) unsigned short Vts[64 * 72];
  __shared__ __align__(16) unsigned short Pt[4 * 32 * 36];

  const int tid = threadIdx.x;
  const int wave = tid >> 6, lane = tid & 63;
  const int q = lane >> 4, ln = lane & 15;
  const int qt = blockIdx.x, h = blockIdx.y, b = blockIdx.z;

  const long baseQ = ((long)b * T_SZ + qt * 128) * D_SZ + h * HD;
  const long baseK = (long)b * T_SZ * D_SZ + h * HD;
  const long baseV = (long)h * HD * M_SZ + (long)b * T_SZ;  // Vt[(h*64+d)][b*2048+t]

  // Q frags straight from global (one-time): A-layout m=ln, k=ks*32+q*8+j
  short8 qf[2][2];
  for (int i = 0; i < 2; ++i)
    for (int ks = 0; ks < 2; ++ks)
      qf[i][ks] = *(const short8*)(Qb + baseQ + (long)(wave * 32 + i * 16 + ln) * D_SZ +
                                   ks * 32 + q * 8);

  float4v o[2][4] = {};
  float lp[2][4] = {};
  unsigned short* Ptw = Pt + wave * 1152;  // 32 keys x pitch 36

  for (int kt = 0; kt < 32; ++kt) {
    __syncthreads();  // previous iteration's frag readers done
    for (int it = 0; it < 2; ++it) {
      int idx = tid + it * 256;
      int row = idx >> 3, cc = idx & 7;
      *(uint4*)(Ks + row * 72 + cc * 8) =
          *(const uint4*)(Kb + baseK + (long)(kt * 64 + row) * D_SZ + cc * 8);
      *(uint4*)(Vts + row * 72 + cc * 8) =
          *(const uint4*)(Vt + baseV + (long)row * M_SZ + kt * 64 + cc * 8);
    }
    __syncthreads();

    // S' = Q' K^T (Q' pre-scaled by log2e)
    short8 kf[4][2];
    for (int c = 0; c < 4; ++c)
      for (int ks = 0; ks < 2; ++ks)
        kf[c][ks] = *(const short8*)(Ks + (c * 16 + ln) * 72 + ks * 32 + q * 8);
    float4v s[2][4];
    for (int i = 0; i < 2; ++i)
      for (int c = 0; c < 4; ++c) {
        float4v z = {};
        z = MFMA16(qf[i][0], kf[c][0], z);
        z = MFMA16(qf[i][1], kf[c][1], z);
        s[i][c] = z;
      }

    // phases over key halves: exp2, pack to Pt[key][qrow], PV MFMA
    for (int ks = 0; ks < 2; ++ks) {
      for (int i = 0; i < 2; ++i)
        for (int cl = 0; cl < 2; ++cl) {
          int c = 2 * ks + cl;
          float p0 = exp2f(s[i][c][0]);
          float p1 = exp2f(s[i][c][1]);
          float p2 = exp2f(s[i][c][2]);
          float p3 = exp2f(s[i][c][3]);
          lp[i][0] += p0; lp[i][1] += p1; lp[i][2] += p2; lp[i][3] += p3;
          __hip_bfloat162 lo = __float22bfloat162_rn(make_float2(p0, p1));
          __hip_bfloat162 hi = __float22bfloat162_rn(make_float2(p2, p3));
          uint2 w;
          w.x = *(unsigned*)&lo;
          w.y = *(unsigned*)&hi;
          *(uint2*)(Ptw + (cl * 16 + ln) * 36 + i * 16 + q * 4) = w;
        }
      short8 vf[4];
      for (int j = 0; j < 4; ++j)
        vf[j] = *(const short8*)(Vts + (j * 16 + ln) * 72 + ks * 32 + q * 8);
      for (int i = 0; i < 2; ++i) {
        short8 pf;
        for (int j8 = 0; j8 < 8; ++j8)
          pf[j8] = (short)Ptw[(q * 8 + j8) * 36 + i * 16 + ln];
        for (int j = 0; j < 4; ++j)
          o[i][j] = MFMA16(pf, vf[j], o[i][j]);
      }
    }
  }

  // epilogue: one cross-lane l reduction, normalize, store
  for (int i = 0; i < 2; ++i)
    for (int r = 0; r < 4; ++r) {
      float l = lp[i][r];
      l += __shfl_xor(l, 1, 64);
      l += __shfl_xor(l, 2, 64);
      l += __shfl_xor(l, 4, 64);
      l += __shfl_xor(l, 8, 64);
      float inv = 1.f / l;
      int row = qt * 128 + wave * 32 + i * 16 + q * 4 + r;
      long base = ((long)b * T_SZ + row) * D_SZ + h * HD;
      for (int j = 0; j < 4; ++j)
        Ob[base + j * 16 + ln] = f2bf(o[i][j][r] * inv);
    }
}

extern "C" void kernel_launch(void* const* d_in, const int* in_sizes, int n_in,
                              void* d_out, int out_size, void* d_ws, size_t ws_size,
                              hipStream_t stream) {
  const float* x = (const float*)d_in[0];
  const float* Wq = (const float*)d_in[1];
  const float* bq = (const float*)d_in[2];
  const float* Wk = (const float*)d_in[3];
  const float* bk = (const float*)d_in[4];
  const float* Wv = (const float*)d_in[5];
  const float* bv = (const float*)d_in[6];
  const float* Wp = (const float*)d_in[7];
  const float* bp = (const float*)d_in[8];
  float* out = (float*)d_out;

  const long MX = (long)M_SZ * D_SZ;  // 8388608
  const long MW = (long)D_SZ * D_SZ;  // 1048576
  unsigned short* ws = (unsigned short*)d_ws;
  unsigned short* xb = ws;
  unsigned short* Wqb = xb + MX;
  unsigned short* Wkb = Wqb + MW;
  unsigned short* Wvb = Wkb + MW;
  unsigned short* Wpb = Wvb + MW;
  unsigned short* Qb = Wpb + MW;
  unsigned short* Kb = Qb + MX;
  unsigned short* Vtb = Kb + MX;
  unsigned short* Ob = Vtb + MX;

  cvt_kernel<<<(int)(MX / 1024), 256, 0, stream>>>(x, xb, 1.0f, MX);
  cvt_kernel<<<(int)(MW / 1024), 256, 0, stream>>>(Wq, Wqb, LOG2E, MW);  // fold log2e into Q
  cvt_kernel<<<(int)(MW / 1024), 256, 0, stream>>>(Wk, Wkb, 1.0f, MW);
  cvt_kernel<<<(int)(MW / 1024), 256, 0, stream>>>(Wv, Wvb, 1.0f, MW);
  cvt_kernel<<<(int)(MW / 1024), 256, 0, stream>>>(Wp, Wpb, 1.0f, MW);

  dim3 gg(D_SZ / 128, M_SZ / 128);  // (8, 64)
  gemm_bt<<<gg, 256, 0, stream>>>(xb, Wqb, bq, LOG2E, Qb, nullptr, M_SZ, D_SZ, D_SZ, 0);
  gemm_bt<<<gg, 256, 0, stream>>>(xb, Wkb, bk, 1.0f, Kb, nullptr, M_SZ, D_SZ, D_SZ, 0);
  // V^T: C[feat][tok] = Wv . x^T  (row bias)
  dim3 gv(M_SZ / 128, D_SZ / 128);  // (64, 8)
  gemm_bt<<<gv, 256, 0, stream>>>(Wvb, xb, bv, 1.0f, Vtb, nullptr, D_SZ, M_SZ, D_SZ, 1);

  dim3 ag(T_SZ / 128, NH, B_SZ);  // (16, 16, 4)
  attn_kernel<<<ag, 256, 0, stream>>>(Qb, Kb, Vtb, Ob);

  gemm_bt<<<gg, 256, 0, stream>>>(Ob, Wpb, bp, 1.0f, nullptr, out, M_SZ, D_SZ, D_SZ, 0);
}

// Round 3
// 319.932 us; speedup vs baseline: 1.5716x; 1.1395x over previous
//
#include <hip/hip_runtime.h>
#include <hip/hip_bf16.h>

// MHA: x[4,2048,1024] fp32, 16 heads x 64, no 1/sqrt(d) scale.
// cvt(x) + cvt(4 weights, Wq*log2e) + bias-concat -> fused QKV gemm (N=3072,
// V-blocks transposed in epilogue) -> flash attention (S^T trick: both sides of
// the P round-trip vectorized; max-free exp2 softmax) -> proj gemm (fp32 out).

typedef short short8 __attribute__((ext_vector_type(8)));
typedef float float4v __attribute__((ext_vector_type(4)));

#define MFMA16(a, b, c) __builtin_amdgcn_mfma_f32_16x16x32_bf16((a), (b), (c), 0, 0, 0)
#define LOG2E 1.4426950408889634f

#define B_SZ 4
#define T_SZ 2048
#define D_SZ 1024
#define NH 16
#define HD 64
#define M_SZ (B_SZ * T_SZ)  // 8192

__device__ __forceinline__ unsigned short f2bf(float f) {
  unsigned int u = __float_as_uint(f);
  u += 0x7fffu + ((u >> 16) & 1u);
  return (unsigned short)(u >> 16);
}

__device__ __forceinline__ void gl_lds16(const unsigned short* g, unsigned short* l) {
  __builtin_amdgcn_global_load_lds(
      (const __attribute__((address_space(1))) unsigned int*)g,
      (__attribute__((address_space(3))) unsigned int*)l, 16, 0, 0);
}

// ---------------- fp32 -> bf16 converts ----------------
__global__ __launch_bounds__(256) void cvt_kernel(const float* __restrict__ in,
                                                  unsigned short* __restrict__ out,
                                                  float scale, long n) {
  long i = ((long)blockIdx.x * 256 + threadIdx.x) * 4;
  if (i >= n) return;
  float4 v = *(const float4*)(in + i);
  uint2 o;
  o.x = (unsigned)f2bf(v.x * scale) | ((unsigned)f2bf(v.y * scale) << 16);
  o.y = (unsigned)f2bf(v.z * scale) | ((unsigned)f2bf(v.w * scale) << 16);
  *(uint2*)(out + i) = o;
}

// 4 weight matrices -> contiguous bf16 [Wq*log2e; Wk; Wv; Wp]
__global__ __launch_bounds__(256) void cvt_w(const float* __restrict__ w0,
                                             const float* __restrict__ w1,
                                             const float* __restrict__ w2,
                                             const float* __restrict__ w3,
                                             unsigned short* __restrict__ out, long per) {
  long i = ((long)blockIdx.x * 256 + threadIdx.x) * 4;
  int which = (int)(i / per);
  const float* src = which == 0 ? w0 : which == 1 ? w1 : which == 2 ? w2 : w3;
  float scale = which == 0 ? LOG2E : 1.0f;
  long j = i - (long)which * per;
  float4 v = *(const float4*)(src + j);
  uint2 o;
  o.x = (unsigned)f2bf(v.x * scale) | ((unsigned)f2bf(v.y * scale) << 16);
  o.y = (unsigned)f2bf(v.z * scale) | ((unsigned)f2bf(v.w * scale) << 16);
  *(uint2*)(out + i) = o;
}

__global__ __launch_bounds__(256) void cvt_bias(const float* __restrict__ b0,
                                                const float* __restrict__ b1,
                                                const float* __restrict__ b2,
                                                float* __restrict__ out) {
  int i = blockIdx.x * 256 + threadIdx.x;  // 0..3071
  float v;
  if (i < 1024) v = b0[i] * LOG2E;
  else if (i < 2048) v = b1[i - 1024];
  else v = b2[i - 2048];
  out[i] = v;
}

// ---------------- fused QKV gemm: C[8192,3072] = x . [Wq;Wk;Wv]^T + b ----------------
// m97 core: 128x128 tile, BK=64, global_load_lds w=16. V col-blocks (n0>=2048)
// transpose their tile through LDS and store V^T[feat][tok].
__global__ __launch_bounds__(256, 2) void gemm_qkv(const unsigned short* __restrict__ A,
                                                   const unsigned short* __restrict__ W,
                                                   const float* __restrict__ bias,
                                                   unsigned short* __restrict__ Qb,
                                                   unsigned short* __restrict__ Kb,
                                                   unsigned short* __restrict__ Vt) {
  __shared__ __align__(16) unsigned short smem[17408];  // As|Bs (16K shorts) / Ct (128x136)
  unsigned short* As = smem;
  unsigned short* Bs = smem + 8192;
  unsigned short* Ct = smem;
  const int tid = threadIdx.x;
  const int wave = tid >> 6, lane = tid & 63;
  const int q = lane >> 4, ln = lane & 15;
  const int wm = (wave >> 1) * 64, wn = (wave & 1) * 64;
  const long m0 = (long)blockIdx.y * 128;
  const long n0 = (long)blockIdx.x * 128;
  const int srow = lane >> 3, scol = (lane & 7) * 8;
  const int K = D_SZ;

  float4v acc[4][4] = {};

  for (int k0 = 0; k0 < K; k0 += 64) {
    for (int t = 0; t < 4; ++t) {
      int seg = wave * 4 + t;
      int row = seg * 8 + srow;
      gl_lds16(A + (m0 + row) * (long)K + k0 + scol, As + seg * 512);
      gl_lds16(W + (n0 + row) * (long)K + k0 + scol, Bs + seg * 512);
    }
    __syncthreads();
    for (int ks = 0; ks < 2; ++ks) {
      short8 af[4], bf[4];
      for (int i = 0; i < 4; ++i)
        af[i] = *(const short8*)(As + (wm + i * 16 + ln) * 64 + ks * 32 + q * 8);
      for (int j = 0; j < 4; ++j)
        bf[j] = *(const short8*)(Bs + (wn + j * 16 + ln) * 64 + ks * 32 + q * 8);
      for (int i = 0; i < 4; ++i)
        for (int j = 0; j < 4; ++j)
          acc[i][j] = MFMA16(af[i], bf[j], acc[i][j]);
    }
    __syncthreads();
  }

  if ((int)n0 < 2048) {
    unsigned short* dst = (int)n0 < 1024 ? Qb : Kb;
    int coff = (int)n0 < 1024 ? 0 : 1024;
    for (int i = 0; i < 4; ++i) {
      long rowb = m0 + wm + i * 16 + q * 4;
      for (int j = 0; j < 4; ++j) {
        long col = n0 + wn + j * 16 + ln;
        float bv = bias[col];
        for (int r = 0; r < 4; ++r)
          dst[(rowb + r) * (long)D_SZ + col - coff] = f2bf(acc[i][j][r] + bv);
      }
    }
  } else {
    // transpose 128x128 tile: Ct[col_local][row_local], packed b64 over r
    for (int i = 0; i < 4; ++i)
      for (int j = 0; j < 4; ++j) {
        int col_l = wn + j * 16 + ln;
        float bv = bias[n0 + col_l];
        __hip_bfloat162 lo =
            __float22bfloat162_rn(make_float2(acc[i][j][0] + bv, acc[i][j][1] + bv));
        __hip_bfloat162 hi =
            __float22bfloat162_rn(make_float2(acc[i][j][2] + bv, acc[i][j][3] + bv));
        uint2 w;
        w.x = *(unsigned*)&lo;
        w.y = *(unsigned*)&hi;
        *(uint2*)(Ct + col_l * 136 + wm + i * 16 + q * 4) = w;
      }
    __syncthreads();
    for (int it = 0; it < 8; ++it) {
      int idx = tid + it * 256;
      int c = idx >> 4, rb = idx & 15;
      uint4 v = *(const uint4*)(Ct + c * 136 + rb * 8);
      *(uint4*)(Vt + (n0 - 2048 + c) * (long)M_SZ + m0 + rb * 8) = v;
    }
  }
}

// ---------------- proj gemm: out[8192,1024] = Ob . Wp^T + bp (fp32) ----------------
__global__ __launch_bounds__(256, 2) void gemm_proj(const unsigned short* __restrict__ A,
                                                    const unsigned short* __restrict__ W,
                                                    const float* __restrict__ bias,
                                                    float* __restrict__ Cf) {
  __shared__ __align__(16) unsigned short As[128 * 64];
  __shared__ __align__(16) unsigned short Bs[128 * 64];
  const int tid = threadIdx.x;
  const int wave = tid >> 6, lane = tid & 63;
  const int q = lane >> 4, ln = lane & 15;
  const int wm = (wave >> 1) * 64, wn = (wave & 1) * 64;
  const long m0 = (long)blockIdx.y * 128;
  const long n0 = (long)blockIdx.x * 128;
  const int srow = lane >> 3, scol = (lane & 7) * 8;
  const int K = D_SZ;

  float4v acc[4][4] = {};
  for (int k0 = 0; k0 < K; k0 += 64) {
    for (int t = 0; t < 4; ++t) {
      int seg = wave * 4 + t;
      int row = seg * 8 + srow;
      gl_lds16(A + (m0 + row) * (long)K + k0 + scol, As + seg * 512);
      gl_lds16(W + (n0 + row) * (long)K + k0 + scol, Bs + seg * 512);
    }
    __syncthreads();
    for (int ks = 0; ks < 2; ++ks) {
      short8 af[4], bf[4];
      for (int i = 0; i < 4; ++i)
        af[i] = *(const short8*)(As + (wm + i * 16 + ln) * 64 + ks * 32 + q * 8);
      for (int j = 0; j < 4; ++j)
        bf[j] = *(const short8*)(Bs + (wn + j * 16 + ln) * 64 + ks * 32 + q * 8);
      for (int i = 0; i < 4; ++i)
        for (int j = 0; j < 4; ++j)
          acc[i][j] = MFMA16(af[i], bf[j], acc[i][j]);
    }
    __syncthreads();
  }
  for (int i = 0; i < 4; ++i) {
    long rowb = m0 + wm + i * 16 + q * 4;
    for (int j = 0; j < 4; ++j) {
      long col = n0 + wn + j * 16 + ln;
      float bv = bias[col];
      for (int r = 0; r < 4; ++r)
        Cf[(rowb + r) * (long)D_SZ + col] = acc[i][j][r] + bv;
    }
  }
}

// ---------------- flash attention (S^T trick, max-free exp2 softmax) ----------------
// block = (q-tile 128, head, batch); 4 waves x 32 q-rows; kv tiles of 64.
// QK^T computed transposed (A=K, B=Q) so each lane holds 4 consecutive keys per
// q-row -> P lands in LDS in A-operand layout with b64 writes / b128 reads.
__global__ __launch_bounds__(256, 4) void attn_kernel(const unsigned short* __restrict__ Qb,
                                                      const unsigned short* __restrict__ Kb,
                                                      const unsigned short* __restrict__ Vt,
                                                      unsigned short* __restrict__ Ob) {
  __shared__ __align__(16) unsigned short Ks[64 * 72];
  __shared__ __align__(16) unsigned short Vts[64 * 72];
  __shared__ __align__(16) unsigned short Ps[4 * 32 * 72];  // per-wave [qrow][key]

  const int tid = threadIdx.x;
  const int wave = tid >> 6, lane = tid & 63;
  const int q = lane >> 4, ln = lane & 15;
  const int qt = blockIdx.x, h = blockIdx.y, b = blockIdx.z;

  const long baseQ = ((long)b * T_SZ + qt * 128) * D_SZ + h * HD;
  const long baseK = (long)b * T_SZ * D_SZ + h * HD;
  const long baseV = (long)h * HD * M_SZ + (long)b * T_SZ;

  short8 qf[2][2];
  for (int i = 0; i < 2; ++i)
    for (int ks = 0; ks < 2; ++ks)
      qf[i][ks] = *(const short8*)(Qb + baseQ + (long)(wave * 32 + i * 16 + ln) * D_SZ +
                                   ks * 32 + q * 8);

  float4v o[2][4] = {};
  float lp[2] = {};
  unsigned short* Psw = Ps + wave * (32 * 72);

  for (int kt = 0; kt < 32; ++kt) {
    __syncthreads();
    for (int it = 0; it < 2; ++it) {
      int idx = tid + it * 256;
      int row = idx >> 3, cc = idx & 7;
      *(uint4*)(Ks + row * 72 + cc * 8) =
          *(const uint4*)(Kb + baseK + (long)(kt * 64 + row) * D_SZ + cc * 8);
      *(uint4*)(Vts + row * 72 + cc * 8) =
          *(const uint4*)(Vt + baseV + (long)row * M_SZ + kt * 64 + cc * 8);
    }
    __syncthreads();

    // S^T = K Q'^T ; D: row = key-part (q*4+r), col = qrow-part (ln)
    short8 kf[4][2];
    for (int c = 0; c < 4; ++c)
      for (int ks = 0; ks < 2; ++ks)
        kf[c][ks] = *(const short8*)(Ks + (c * 16 + ln) * 72 + ks * 32 + q * 8);
    float4v s[4][2];
    for (int c = 0; c < 4; ++c)
      for (int i = 0; i < 2; ++i) {
        float4v z = {};
        z = MFMA16(kf[c][0], qf[i][0], z);
        z = MFMA16(kf[c][1], qf[i][1], z);
        s[c][i] = z;
      }

    // exp2, accumulate row-sum, write P[qrow][key] (keys q*4+r consecutive -> b64)
    for (int i = 0; i < 2; ++i)
      for (int c = 0; c < 4; ++c) {
        float p0 = exp2f(s[c][i][0]);
        float p1 = exp2f(s[c][i][1]);
        float p2 = exp2f(s[c][i][2]);
        float p3 = exp2f(s[c][i][3]);
        lp[i] += (p0 + p1) + (p2 + p3);
        __hip_bfloat162 lo = __float22bfloat162_rn(make_float2(p0, p1));
        __hip_bfloat162 hi = __float22bfloat162_rn(make_float2(p2, p3));
        uint2 w;
        w.x = *(unsigned*)&lo;
        w.y = *(unsigned*)&hi;
        *(uint2*)(Psw + (i * 16 + ln) * 72 + c * 16 + q * 4) = w;
      }

    // O += P V : A = P frags (vector b128), B = V^T frags
    short8 pf[2][2], vf[4][2];
    for (int i = 0; i < 2; ++i)
      for (int ks = 0; ks < 2; ++ks)
        pf[i][ks] = *(const short8*)(Psw + (i * 16 + ln) * 72 + ks * 32 + q * 8);
    for (int j = 0; j < 4; ++j)
      for (int ks = 0; ks < 2; ++ks)
        vf[j][ks] = *(const short8*)(Vts + (j * 16 + ln) * 72 + ks * 32 + q * 8);
    for (int i = 0; i < 2; ++i)
      for (int j = 0; j < 4; ++j) {
        o[i][j] = MFMA16(pf[i][0], vf[j][0], o[i][j]);
        o[i][j] = MFMA16(pf[i][1], vf[j][1], o[i][j]);
      }
  }

  // epilogue: reduce l over quads, fetch per-row inv via shfl, store
  for (int i = 0; i < 2; ++i) {
    float l = lp[i];
    l += __shfl_xor(l, 16, 64);
    l += __shfl_xor(l, 32, 64);
    float inv = 1.f / l;  // lane holds qrow = i*16+ln
    for (int r = 0; r < 4; ++r) {
      int src = (lane & 48) | (q * 4 + r);
      float invr = __shfl(inv, src, 64);
      int row = qt * 128 + wave * 32 + i * 16 + q * 4 + r;
      long base = ((long)b * T_SZ + row) * D_SZ + h * HD;
      for (int j = 0; j < 4; ++j)
        Ob[base + j * 16 + ln] = f2bf(o[i][j][r] * invr);
    }
  }
}

extern "C" void kernel_launch(void* const* d_in, const int* in_sizes, int n_in,
                              void* d_out, int out_size, void* d_ws, size_t ws_size,
                              hipStream_t stream) {
  const float* x = (const float*)d_in[0];
  const float* Wq = (const float*)d_in[1];
  const float* bq = (const float*)d_in[2];
  const float* Wk = (const float*)d_in[3];
  const float* bk = (const float*)d_in[4];
  const float* Wv = (const float*)d_in[5];
  const float* bv = (const float*)d_in[6];
  const float* Wp = (const float*)d_in[7];
  const float* bp = (const float*)d_in[8];
  float* out = (float*)d_out;

  const long MX = (long)M_SZ * D_SZ;  // 8388608
  const long MW = (long)D_SZ * D_SZ;  // 1048576
  unsigned short* ws = (unsigned short*)d_ws;
  unsigned short* xb = ws;
  unsigned short* Wcat = xb + MX;          // [Wq*log2e; Wk; Wv; Wp]
  float* bcat = (float*)(Wcat + 4 * MW);   // 3072 fp32
  unsigned short* Qb = (unsigned short*)(bcat + 3072);
  unsigned short* Kb = Qb + MX;
  unsigned short* Vtb = Kb + MX;
  unsigned short* Ob = Vtb + MX;

  cvt_kernel<<<(int)(MX / 1024), 256, 0, stream>>>(x, xb, 1.0f, MX);
  cvt_w<<<(int)(4 * MW / 1024), 256, 0, stream>>>(Wq, Wk, Wv, Wp, Wcat, MW);
  cvt_bias<<<12, 256, 0, stream>>>(bq, bk, bv, bcat);

  dim3 gq(3072 / 128, M_SZ / 128);  // (24, 64)
  gemm_qkv<<<gq, 256, 0, stream>>>(xb, Wcat, bcat, Qb, Kb, Vtb);

  dim3 ag(T_SZ / 128, NH, B_SZ);  // (16, 16, 4)
  attn_kernel<<<ag, 256, 0, stream>>>(Qb, Kb, Vtb, Ob);

  dim3 gp(D_SZ / 128, M_SZ / 128);  // (8, 64)
  gemm_proj<<<gp, 256, 0, stream>>>(Ob, Wcat + 3 * MW, bp, out);
}